// Round 18
// baseline (134.815 us; speedup 1.0000x reference)
//
#include <hip/hip_runtime.h>

#define TL 2048
#define NHEAD 8
#define NLOC 4
#define L2E 1.44269504f
#define PSTRIDE 4352   // f32 per partial: 4096 (32dp x 128q u32 bf16x2) + 128 l

typedef __attribute__((ext_vector_type(4))) float f32x4;
typedef __attribute__((ext_vector_type(16))) float f32x16;
typedef __attribute__((ext_vector_type(8))) __bf16 bf16x8;
typedef __attribute__((ext_vector_type(8))) unsigned short u16x8;
typedef __attribute__((ext_vector_type(4))) unsigned int u32x4;

static __device__ __forceinline__ unsigned short f2bf(float f) {
    unsigned u = __float_as_uint(f);
    u = (u + 0x7FFFu + ((u >> 16) & 1u)) >> 16;
    return (unsigned short)u;
}
static __device__ __forceinline__ unsigned int cvtpk(float a, float b) {
    unsigned int w;
    asm("v_cvt_pk_bf16_f32 %0, %1, %2" : "=v"(w) : "v"(a), "v"(b));
    return w;
}

// blocks < 1024: K tile -> fragment-linear bf16 (per (h2,mq): 64 lanes x 16B),
//   V tile -> fragment-linear TRANSPOSED bf16 (per (c2,half): 64 lanes x 16B).
//   Fused v_term f32 (local heads).
// blocks >= 1024: rel_scores[h', r] = dot(rel_pos_w[r,h'*64:+64], mlp_w[h'])*L2E
__global__ __launch_bounds__(256) void preconv_kernel(
    const float* __restrict__ key, const float* __restrict__ value,
    const float* __restrict__ mlp_w, const float* __restrict__ rel_pos_w,
    unsigned short* __restrict__ Kb, unsigned short* __restrict__ Vtb,
    float* __restrict__ vtbf, float* __restrict__ rel_sf) {
    int blk = blockIdx.x;
    int t = threadIdx.x;
    int wave = t >> 6, lane = t & 63;

    if (blk >= 1024) {
        int r = (blk - 1024) * 4 + wave;
        if (r < 2 * TL - 1) {
#pragma unroll
            for (int hp = 0; hp < 4; ++hp) {
                float v = rel_pos_w[r * 256 + hp * 64 + lane] * mlp_w[hp * 64 + lane];
#pragma unroll
                for (int off = 32; off; off >>= 1) v += __shfl_xor(v, off);
                if (lane == 0) rel_sf[hp * 4096 + r] = v * L2E;
            }
        }
        return;
    }

    __shared__ float Tf[64][66];
    int bh = blk >> 5, kt = blk & 31;
    int h = bh & 7, b = bh >> 3;
    size_t src = (size_t)blk * 4096;
    size_t dst = (size_t)blk * 4096;

    // ---- K phase: coalesced load -> LDS -> fragment-linear store ----
    {
        int row = t >> 2, q4 = t & 3;
        const float* kp = key + src + row * 64 + q4 * 16;
#pragma unroll
        for (int j = 0; j < 4; ++j)
            *(f32x4*)&Tf[row][q4 * 16 + j * 4] = *(const f32x4*)(kp + j * 4);
    }
    __syncthreads();
#pragma unroll
    for (int i = 0; i < 2; ++i) {
        int idx = t + i * 256;
        int l31 = idx & 31, hi = (idx >> 5) & 1, mq = (idx >> 6) & 3, h2 = idx >> 8;
        int r = h2 * 32 + l31, c = mq * 2 + hi;
        u16x8 o;
#pragma unroll
        for (int j = 0; j < 8; ++j) o[j] = f2bf(Tf[r][c * 8 + j]);
        *(u16x8*)&Kb[dst + idx * 8] = o;
    }
    __syncthreads();

    // ---- V phase: coalesced load -> LDS -> TRANSPOSED fragment store ----
    {
        int row = t >> 2, q4 = t & 3;
        const float* vp = value + src + row * 64 + q4 * 16;
#pragma unroll
        for (int j = 0; j < 4; ++j)
            *(f32x4*)&Tf[row][q4 * 16 + j * 4] = *(const f32x4*)(vp + j * 4);
    }
    __syncthreads();
#pragma unroll
    for (int i = 0; i < 2; ++i) {
        int idx = t + i * 256;
        int l31 = idx & 31, hi = (idx >> 5) & 1, half = (idx >> 6) & 1, c2 = idx >> 7;
        int r = half * 32 + l31, c = c2 * 2 + hi;
        u16x8 o;
#pragma unroll
        for (int j = 0; j < 8; ++j) o[j] = f2bf(Tf[c * 8 + j][r]);
        *(u16x8*)&Vtb[dst + idx * 8] = o;
    }
    if (h >= NLOC) {
        float mw = mlp_w[(h - NLOC) * 64 + lane];
        float* vout = vtbf + (size_t)((b * NLOC + h - NLOC) * TL) + kt * 64;
#pragma unroll
        for (int i = 0; i < 16; ++i) {
            int row = wave * 16 + i;
            float v = Tf[row][lane] * mw;
#pragma unroll
            for (int off = 32; off; off >>= 1) v += __shfl_xor(v, off);
            if (lane == 0) vout[row] = v * L2E;
        }
    }
}

#define MFMA32(A, B, C) __builtin_amdgcn_mfma_f32_32x32x16_bf16(A, B, C, 0, 0, 0)

// Flash attention, 32x32 MFMA, swapped QK^T, in-register P, fixed-exponent
// softmax (P = exp2(S-20)). SINGLE LDS buffer + REGISTER staging (T14):
// next tile held in 16 VGPRs, ds_write after compute barrier; global loads
// for tile+2 issued right after (latency hidden under a full tile).
// LDS 18.9 KB -> 6 blocks/CU (24 waves) vs r17's 4 (16 waves).
__global__ __launch_bounds__(256, 6) void attn_kernel(
    const float* __restrict__ query,
    const unsigned short* __restrict__ Kb, const unsigned short* __restrict__ Vtb,
    const float* __restrict__ rel_sf, const float* __restrict__ vtbf,
    float* __restrict__ part) {

    __shared__ __align__(16) unsigned char smem[19456];
    unsigned short* Ks  = (unsigned short*)smem;            // [4096] u16
    unsigned short* Vt  = (unsigned short*)(smem + 8192);   // [4096] u16
    float* relw  = (float*)(smem + 16384);                  // [512] f32, pre-offset -20
    float* biasf = (float*)(smem + 18432);                  // [2][64] f32

    int bid = blockIdx.x;          // 1632 = 51 sids x 32 bhx
    int bhx = bid & 31;
    int bh = (bhx & 7) * 4 + (bhx >> 3);   // 4 bh per XCD (bid%8 locality)
    int sid = bid >> 5;
    // sid -> (i, s): rows i=15..0, n_i = ceil((2i+2)/6) strips, sizes {T,T+1}
    int i = 0, s = 0, acc = 0;
    for (int ii = 15; ii >= 0; --ii) {
        int ns = (2 * ii + 7) / 6;
        if (sid >= acc && sid < acc + ns) { i = ii; s = sid - acc; }
        acc += ns;
    }
    int nt = 2 * i + 2;
    int n = (2 * i + 7) / 6;
    int T = nt / n, R = nt % n;
    int k_b = s * T + min(s, R);
    int len = T + (s < R ? 1 : 0);
    int q0 = i << 7;

    int h = bh & 7, b = bh >> 3;
    bool islocal = (h >= NLOC);
    int t = threadIdx.x;
    int w = t >> 6;                // 0..3
    int l31 = t & 31;
    int hi = (t >> 5) & 1;
    int qrel = 32 * w + l31;       // 0..127
    int qglob = q0 + qrel;
    int qmaxw = q0 + 32 * w + 31;
    int hivl = hi * 256 + l31 * 8; // u16 elems: lane slot within a 1KB fragment

    size_t tbase = (size_t)bh * 32 * 4096;
    const unsigned short* Ktiles = Kb + tbase;
    const unsigned short* Vtiles = Vtb + tbase;
    const float* vtpf = vtbf + (islocal ? (size_t)((b * NLOC + h - NLOC) * TL) : 0);
    int idxlo = 64 * k_b - q0 + 1920;                  // multiple of 64, >= 0
    const float* relsrc = rel_sf + (islocal ? ((h - NLOC) * 4096 + idxlo) : 0);

    // ---- prologue: tile k_b -> LDS (via regs); tile k_b+1 -> regs ----
    u16x8 krA, krB, vrA, vrB;
    {
        const unsigned short* gk = Ktiles + (size_t)k_b * 4096;
        const unsigned short* gv = Vtiles + (size_t)k_b * 4096;
        krA = *(const u16x8*)(gk + t * 8);
        krB = *(const u16x8*)(gk + 2048 + t * 8);
        vrA = *(const u16x8*)(gv + t * 8);
        vrB = *(const u16x8*)(gv + 2048 + t * 8);
        *(u16x8*)&Ks[t * 8] = krA;
        *(u16x8*)&Ks[2048 + t * 8] = krB;
        *(u16x8*)&Vt[t * 8] = vrA;
        *(u16x8*)&Vt[2048 + t * 8] = vrB;
    }
    if (len > 1) {
        const unsigned short* gk = Ktiles + (size_t)(k_b + 1) * 4096;
        const unsigned short* gv = Vtiles + (size_t)(k_b + 1) * 4096;
        krA = *(const u16x8*)(gk + t * 8);
        krB = *(const u16x8*)(gk + 2048 + t * 8);
        vrA = *(const u16x8*)(gv + t * 8);
        vrB = *(const u16x8*)(gv + 2048 + t * 8);
    }
    if (islocal) {
        if (t < 128) {
            f32x4 v = ((const f32x4*)relsrc)[t];
            ((f32x4*)relw)[t] = v - 20.0f;
        }
        if (t < 16) ((f32x4*)biasf)[t] = ((const f32x4*)(vtpf + (size_t)k_b * 64))[t];
    }

    // Q fragments (B-operand): col q = lane&31, d = 16*mq + 8*hi + e
    const float SC = 0.125f * L2E;
    bf16x8 qf[4];
    {
        const float* qsrc = query + ((size_t)bh * TL + qglob) * 64 + 8 * hi;
#pragma unroll
        for (int mq = 0; mq < 4; ++mq) {
            f32x4 a = *(const f32x4*)(qsrc + 16 * mq);
            f32x4 c = *(const f32x4*)(qsrc + 16 * mq + 4);
            u16x8 u;
#pragma unroll
            for (int j = 0; j < 4; ++j) { u[j] = f2bf(a[j] * SC); u[4 + j] = f2bf(c[j] * SC); }
            qf[mq] = __builtin_bit_cast(bf16x8, u);
        }
    }

    float lsum = 0.f;
    f32x16 O0 = {0,0,0,0,0,0,0,0,0,0,0,0,0,0,0,0};
    f32x16 O1 = {0,0,0,0,0,0,0,0,0,0,0,0,0,0,0,0};

    __syncthreads();   // tile k_b + relw + biasf ready

    int cur = 0;
#pragma unroll 1
    for (int kt4 = 0; kt4 < len; ++kt4) {
        int kt = k_b + kt4;
        const float* bias = biasf + cur * 64;

        bool active = (64 * kt <= qmaxw);           // wave-uniform; NO break
        bool maskt = (64 * kt + 63 > q0 + 32 * w);  // tile crosses diagonal
        if (active) {
#pragma unroll
            for (int h2 = 0; h2 < 2; ++h2) {
                // ---- seed C with rel+bias-20 (local) or -20, S += K^T Q ----
                f32x16 S;
                if (islocal) {
                    int rbase = 64 * kt4 + 32 * h2 + 4 * hi + 127 - qrel;
#pragma unroll
                    for (int g = 0; g < 4; ++g) {
                        f32x4 bv = *(const f32x4*)&bias[32 * h2 + 8 * g + 4 * hi];
#pragma unroll
                        for (int j = 0; j < 4; ++j)
                            S[4 * g + j] = bv[j] + relw[rbase + 8 * g + j];
                    }
                } else {
                    S = (f32x16){-20.f,-20.f,-20.f,-20.f,-20.f,-20.f,-20.f,-20.f,
                                 -20.f,-20.f,-20.f,-20.f,-20.f,-20.f,-20.f,-20.f};
                }
                __builtin_amdgcn_s_setprio(1);
#pragma unroll
                for (int mq = 0; mq < 4; ++mq) {
                    const bf16x8 kf = *(const bf16x8*)&Ks[(h2 * 4 + mq) * 512 + hivl];
                    S = MFMA32(kf, qf[mq], S);
                }
                __builtin_amdgcn_s_setprio(0);
                // lane: q = qglob; k = 64kt + 32h2 + (r&3) + 8(r>>2) + 4hi

                if (maskt) {
                    int koff = 64 * kt + 32 * h2 + 4 * hi - qglob;
#pragma unroll
                    for (int r = 0; r < 16; ++r) {
                        int kk = (r & 3) + 8 * (r >> 2);
                        if (koff + kk > 0) S[r] = -1e30f;
                    }
                }
                // ---- fixed-exponent softmax: P = exp2(S), S pre-offset -20 ----
                float ps = 0.f;
#pragma unroll
                for (int r = 0; r < 16; ++r) {
                    float p = exp2f(S[r]);
                    S[r] = p; ps += p;
                }
                ps += __shfl_xor(ps, 32);
                lsum += ps;

                // ---- P -> bf16 frags via v_permlane32_swap_b32, PV ----
                __builtin_amdgcn_s_setprio(1);
#pragma unroll
                for (int kq = 0; kq < 2; ++kq) {
                    int ra = 8 * kq;
                    unsigned int x0 = cvtpk(S[ra + 0], S[ra + 1]);
                    unsigned int x1 = cvtpk(S[ra + 2], S[ra + 3]);
                    unsigned int y0 = cvtpk(S[ra + 4], S[ra + 5]);
                    unsigned int y1 = cvtpk(S[ra + 6], S[ra + 7]);
                    asm("v_permlane32_swap_b32 %0, %1" : "+v"(x0), "+v"(y0));
                    asm("v_permlane32_swap_b32 %0, %1" : "+v"(x1), "+v"(y1));
                    u32x4 fw;
                    fw[0] = x0; fw[1] = x1; fw[2] = y0; fw[3] = y1;
                    const bf16x8 pf = __builtin_bit_cast(bf16x8, fw);
                    int c2 = h2 * 2 + kq;
                    const bf16x8 vf0 = *(const bf16x8*)&Vt[c2 * 1024 + hivl];
                    const bf16x8 vf1 = *(const bf16x8*)&Vt[c2 * 1024 + 512 + hivl];
                    O0 = MFMA32(vf0, pf, O0);
                    O1 = MFMA32(vf1, pf, O1);
                }
                __builtin_amdgcn_s_setprio(0);
            }
        }
        __syncthreads();   // all waves done READING Ks/Vt for tile kt

        // ---- write staged tile kt+1 from regs; start loads for kt+2 ----
        if (kt4 + 1 < len) {
            *(u16x8*)&Ks[t * 8] = krA;
            *(u16x8*)&Ks[2048 + t * 8] = krB;
            *(u16x8*)&Vt[t * 8] = vrA;
            *(u16x8*)&Vt[2048 + t * 8] = vrB;
            int nb = cur ^ 1;
            if (islocal && t < 16)
                ((f32x4*)(biasf + nb * 64))[t] =
                    ((const f32x4*)(vtpf + (size_t)(kt + 1) * 64))[t];
            if (kt4 + 2 < len) {
                const unsigned short* gk = Ktiles + (size_t)(kt + 2) * 4096;
                const unsigned short* gv = Vtiles + (size_t)(kt + 2) * 4096;
                krA = *(const u16x8*)(gk + t * 8);
                krB = *(const u16x8*)(gk + 2048 + t * 8);
                vrA = *(const u16x8*)(gv + t * 8);
                vrB = *(const u16x8*)(gv + 2048 + t * 8);
            }
            __syncthreads();   // tile kt+1 visible to all waves
            cur = nb;
        }
    }

    // ---- partial dump: [dp 32][q 128] u32 (bf16 pair), then l ----
    float* pp = part + (size_t)bid * PSTRIDE;
    unsigned int* po = (unsigned int*)pp;
#pragma unroll
    for (int g = 0; g < 4; ++g) {
        unsigned int w0 = cvtpk(O0[4 * g + 0], O0[4 * g + 1]);
        unsigned int w1 = cvtpk(O0[4 * g + 2], O0[4 * g + 3]);
        unsigned int w2 = cvtpk(O1[4 * g + 0], O1[4 * g + 1]);
        unsigned int w3 = cvtpk(O1[4 * g + 2], O1[4 * g + 3]);
        int dp0 = 4 * g + 2 * hi;
        po[dp0 * 128 + qrel] = w0;
        po[(dp0 + 1) * 128 + qrel] = w1;
        po[(16 + dp0) * 128 + qrel] = w2;
        po[(16 + dp0 + 1) * 128 + qrel] = w3;
    }
    if (hi == 0) pp[4096 + qrel] = lsum;
}

// Combine strips of each (bhx, q128-block): fixed common exponent -> plain sum.
__global__ __launch_bounds__(128) void merge_kernel(
    const float* __restrict__ part, float* __restrict__ out) {
    int bid = blockIdx.x;          // 512 = 16 i x 32 bhx
    int bhx = bid & 31, i = bid >> 5;
    int bh = (bhx & 7) * 4 + (bhx >> 3);
    int n = (2 * i + 7) / 6;
    int sb = 0;
    for (int ii = 15; ii > i; --ii) sb += (2 * ii + 7) / 6;
    int t = threadIdx.x;           // q = t

    float den = 0.f;
#pragma unroll
    for (int s2 = 0; s2 < 6; ++s2)
        if (s2 < n)
            den += part[(size_t)((sb + s2) * 32 + bhx) * PSTRIDE + 4096 + t];
    float inv = 1.0f / den;

    size_t obase = (size_t)bh * TL * 64 + (size_t)(128 * i + t) * 64;
    for (int seg = 0; seg < 4; ++seg) {
        float o[16];
#pragma unroll
        for (int j = 0; j < 16; ++j) o[j] = 0.f;
#pragma unroll
        for (int s2 = 0; s2 < 6; ++s2) {
            if (s2 < n) {
                const unsigned int* po =
                    (const unsigned int*)(part + (size_t)((sb + s2) * 32 + bhx) * PSTRIDE);
#pragma unroll
                for (int j = 0; j < 8; ++j) {
                    unsigned int wv = po[(seg * 8 + j) * 128 + t];
                    o[2 * j]     += __uint_as_float((wv & 0xffffu) << 16);
                    o[2 * j + 1] += __uint_as_float(wv & 0xffff0000u);
                }
            }
        }
#pragma unroll
        for (int j = 0; j < 16; ++j) o[j] *= inv;
#pragma unroll
        for (int c = 0; c < 4; ++c)
            *(f32x4*)(out + obase + seg * 16 + 4 * c) = *(const f32x4*)&o[4 * c];
    }
}

extern "C" void kernel_launch(void* const* d_in, const int* in_sizes, int n_in,
                              void* d_out, int out_size, void* d_ws, size_t ws_size,
                              hipStream_t stream) {
    const float* query = (const float*)d_in[0];
    const float* key = (const float*)d_in[1];
    const float* value = (const float*)d_in[2];
    const float* rel_pos_w = (const float*)d_in[5];
    const float* mlp_w = (const float*)d_in[8];
    float* out = (float*)d_out;

    unsigned short* Kb = (unsigned short*)d_ws;          // 8 MiB
    unsigned short* Vtb = Kb + 32 * 32 * 4096;           // 8 MiB
    float* rel_sf = (float*)(Vtb + 32 * 32 * 4096);      // 4*4096 f32
    float* vtbf = rel_sf + 4 * 4096;                     // 32768 f32
    float* part = vtbf + 32768;                          // 1632 * 4352 f32 ~ 28.4 MiB

    preconv_kernel<<<2048, 256, 0, stream>>>(key, value, mlp_w, rel_pos_w,
                                             Kb, Vtb, vtbf, rel_sf);
    attn_kernel<<<1632, 256, 0, stream>>>(query, Kb, Vtb, rel_sf, vtbf, part);
    merge_kernel<<<512, 128, 0, stream>>>(part, out);
}

// Round 19
// 73.987 us; speedup vs baseline: 1.8222x; 1.8222x over previous
//
#include <hip/hip_runtime.h>

#define TL 2048
#define NHEAD 8
#define NLOC 4
#define L2E 1.44269504f
#define PSTRIDE 4352   // f32 per partial: 4096 (32dp x 128q u32 bf16x2) + 128 l

typedef __attribute__((ext_vector_type(4))) float f32x4;
typedef __attribute__((ext_vector_type(16))) float f32x16;
typedef __attribute__((ext_vector_type(8))) __bf16 bf16x8;
typedef __attribute__((ext_vector_type(8))) unsigned short u16x8;
typedef __attribute__((ext_vector_type(4))) unsigned int u32x4;

static __device__ __forceinline__ unsigned short f2bf(float f) {
    unsigned u = __float_as_uint(f);
    u = (u + 0x7FFFu + ((u >> 16) & 1u)) >> 16;
    return (unsigned short)u;
}
static __device__ __forceinline__ unsigned int cvtpk(float a, float b) {
    unsigned int w;
    asm("v_cvt_pk_bf16_f32 %0, %1, %2" : "=v"(w) : "v"(a), "v"(b));
    return w;
}

// blocks < 1024: K tile -> fragment-linear bf16 (per (h2,mq): 64 lanes x 16B),
//   V tile -> fragment-linear TRANSPOSED bf16 (per (c2,half): 64 lanes x 16B).
//   Fused v_term f32 (local heads).
// blocks >= 1024: rel_scores[h', r] = dot(rel_pos_w[r,h'*64:+64], mlp_w[h'])*L2E
__global__ __launch_bounds__(256) void preconv_kernel(
    const float* __restrict__ key, const float* __restrict__ value,
    const float* __restrict__ mlp_w, const float* __restrict__ rel_pos_w,
    unsigned short* __restrict__ Kb, unsigned short* __restrict__ Vtb,
    float* __restrict__ vtbf, float* __restrict__ rel_sf) {
    int blk = blockIdx.x;
    int t = threadIdx.x;
    int wave = t >> 6, lane = t & 63;

    if (blk >= 1024) {
        int r = (blk - 1024) * 4 + wave;
        if (r < 2 * TL - 1) {
#pragma unroll
            for (int hp = 0; hp < 4; ++hp) {
                float v = rel_pos_w[r * 256 + hp * 64 + lane] * mlp_w[hp * 64 + lane];
#pragma unroll
                for (int off = 32; off; off >>= 1) v += __shfl_xor(v, off);
                if (lane == 0) rel_sf[hp * 4096 + r] = v * L2E;
            }
        }
        return;
    }

    __shared__ float Tf[64][66];
    int bh = blk >> 5, kt = blk & 31;
    int h = bh & 7, b = bh >> 3;
    size_t src = (size_t)blk * 4096;
    size_t dst = (size_t)blk * 4096;

    // ---- K phase: coalesced load -> LDS -> fragment-linear store ----
    {
        int row = t >> 2, q4 = t & 3;
        const float* kp = key + src + row * 64 + q4 * 16;
#pragma unroll
        for (int j = 0; j < 4; ++j)
            *(f32x4*)&Tf[row][q4 * 16 + j * 4] = *(const f32x4*)(kp + j * 4);
    }
    __syncthreads();
#pragma unroll
    for (int i = 0; i < 2; ++i) {
        int idx = t + i * 256;
        int l31 = idx & 31, hi = (idx >> 5) & 1, mq = (idx >> 6) & 3, h2 = idx >> 8;
        int r = h2 * 32 + l31, c = mq * 2 + hi;
        u16x8 o;
#pragma unroll
        for (int j = 0; j < 8; ++j) o[j] = f2bf(Tf[r][c * 8 + j]);
        *(u16x8*)&Kb[dst + idx * 8] = o;
    }
    __syncthreads();

    // ---- V phase: coalesced load -> LDS -> TRANSPOSED fragment store ----
    {
        int row = t >> 2, q4 = t & 3;
        const float* vp = value + src + row * 64 + q4 * 16;
#pragma unroll
        for (int j = 0; j < 4; ++j)
            *(f32x4*)&Tf[row][q4 * 16 + j * 4] = *(const f32x4*)(vp + j * 4);
    }
    __syncthreads();
#pragma unroll
    for (int i = 0; i < 2; ++i) {
        int idx = t + i * 256;
        int l31 = idx & 31, hi = (idx >> 5) & 1, half = (idx >> 6) & 1, c2 = idx >> 7;
        int r = half * 32 + l31, c = c2 * 2 + hi;
        u16x8 o;
#pragma unroll
        for (int j = 0; j < 8; ++j) o[j] = f2bf(Tf[c * 8 + j][r]);
        *(u16x8*)&Vtb[dst + idx * 8] = o;
    }
    if (h >= NLOC) {
        float mw = mlp_w[(h - NLOC) * 64 + lane];
        float* vout = vtbf + (size_t)((b * NLOC + h - NLOC) * TL) + kt * 64;
#pragma unroll
        for (int i = 0; i < 16; ++i) {
            int row = wave * 16 + i;
            float v = Tf[row][lane] * mw;
#pragma unroll
            for (int off = 32; off; off >>= 1) v += __shfl_xor(v, off);
            if (lane == 0) vout[row] = v * L2E;
        }
    }
}

#define MFMA32(A, B, C) __builtin_amdgcn_mfma_f32_32x32x16_bf16(A, B, C, 0, 0, 0)

// Flash attention, 32x32 MFMA, swapped QK^T, in-register P, fixed-exponent
// softmax (P = exp2(S-20)). SINGLE LDS buffer + REGISTER staging (T14):
// next tile held in 16 VGPRs, ds_write after compute barrier; global loads
// for tile+2 issued right after (latency hidden under a full tile).
// LDS 19 KB; __launch_bounds__(256,4) = the ONLY spill-free budget for this
// body (r11/r18: any tighter clamp -> catastrophic scratch spill).
__global__ __launch_bounds__(256, 4) void attn_kernel(
    const float* __restrict__ query,
    const unsigned short* __restrict__ Kb, const unsigned short* __restrict__ Vtb,
    const float* __restrict__ rel_sf, const float* __restrict__ vtbf,
    float* __restrict__ part) {

    __shared__ __align__(16) unsigned char smem[19456];
    unsigned short* Ks  = (unsigned short*)smem;            // [4096] u16
    unsigned short* Vt  = (unsigned short*)(smem + 8192);   // [4096] u16
    float* relw  = (float*)(smem + 16384);                  // [512] f32, pre-offset -20
    float* biasf = (float*)(smem + 18432);                  // [2][64] f32

    int bid = blockIdx.x;          // 1632 = 51 sids x 32 bhx
    int bhx = bid & 31;
    int bh = (bhx & 7) * 4 + (bhx >> 3);   // 4 bh per XCD (bid%8 locality)
    int sid = bid >> 5;
    // sid -> (i, s): rows i=15..0, n_i = ceil((2i+2)/6) strips, sizes {T,T+1}
    int i = 0, s = 0, acc = 0;
    for (int ii = 15; ii >= 0; --ii) {
        int ns = (2 * ii + 7) / 6;
        if (sid >= acc && sid < acc + ns) { i = ii; s = sid - acc; }
        acc += ns;
    }
    int nt = 2 * i + 2;
    int n = (2 * i + 7) / 6;
    int T = nt / n, R = nt % n;
    int k_b = s * T + min(s, R);
    int len = T + (s < R ? 1 : 0);
    int q0 = i << 7;

    int h = bh & 7, b = bh >> 3;
    bool islocal = (h >= NLOC);
    int t = threadIdx.x;
    int w = t >> 6;                // 0..3
    int l31 = t & 31;
    int hi = (t >> 5) & 1;
    int qrel = 32 * w + l31;       // 0..127
    int qglob = q0 + qrel;
    int qmaxw = q0 + 32 * w + 31;
    int hivl = hi * 256 + l31 * 8; // u16 elems: lane slot within a 1KB fragment

    size_t tbase = (size_t)bh * 32 * 4096;
    const unsigned short* Ktiles = Kb + tbase;
    const unsigned short* Vtiles = Vtb + tbase;
    const float* vtpf = vtbf + (islocal ? (size_t)((b * NLOC + h - NLOC) * TL) : 0);
    int idxlo = 64 * k_b - q0 + 1920;                  // multiple of 64, >= 0
    const float* relsrc = rel_sf + (islocal ? ((h - NLOC) * 4096 + idxlo) : 0);

    // ---- prologue: tile k_b -> LDS (via regs); tile k_b+1 -> regs ----
    u16x8 krA, krB, vrA, vrB;
    {
        const unsigned short* gk = Ktiles + (size_t)k_b * 4096;
        const unsigned short* gv = Vtiles + (size_t)k_b * 4096;
        krA = *(const u16x8*)(gk + t * 8);
        krB = *(const u16x8*)(gk + 2048 + t * 8);
        vrA = *(const u16x8*)(gv + t * 8);
        vrB = *(const u16x8*)(gv + 2048 + t * 8);
        *(u16x8*)&Ks[t * 8] = krA;
        *(u16x8*)&Ks[2048 + t * 8] = krB;
        *(u16x8*)&Vt[t * 8] = vrA;
        *(u16x8*)&Vt[2048 + t * 8] = vrB;
    }
    if (len > 1) {
        const unsigned short* gk = Ktiles + (size_t)(k_b + 1) * 4096;
        const unsigned short* gv = Vtiles + (size_t)(k_b + 1) * 4096;
        krA = *(const u16x8*)(gk + t * 8);
        krB = *(const u16x8*)(gk + 2048 + t * 8);
        vrA = *(const u16x8*)(gv + t * 8);
        vrB = *(const u16x8*)(gv + 2048 + t * 8);
    }
    if (islocal) {
        if (t < 128) {
            f32x4 v = ((const f32x4*)relsrc)[t];
            ((f32x4*)relw)[t] = v - 20.0f;
        }
        if (t < 16) ((f32x4*)biasf)[t] = ((const f32x4*)(vtpf + (size_t)k_b * 64))[t];
    }

    // Q fragments (B-operand): col q = lane&31, d = 16*mq + 8*hi + e
    const float SC = 0.125f * L2E;
    bf16x8 qf[4];
    {
        const float* qsrc = query + ((size_t)bh * TL + qglob) * 64 + 8 * hi;
#pragma unroll
        for (int mq = 0; mq < 4; ++mq) {
            f32x4 a = *(const f32x4*)(qsrc + 16 * mq);
            f32x4 c = *(const f32x4*)(qsrc + 16 * mq + 4);
            u16x8 u;
#pragma unroll
            for (int j = 0; j < 4; ++j) { u[j] = f2bf(a[j] * SC); u[4 + j] = f2bf(c[j] * SC); }
            qf[mq] = __builtin_bit_cast(bf16x8, u);
        }
    }

    float lsum = 0.f;
    f32x16 O0 = {0,0,0,0,0,0,0,0,0,0,0,0,0,0,0,0};
    f32x16 O1 = {0,0,0,0,0,0,0,0,0,0,0,0,0,0,0,0};

    __syncthreads();   // tile k_b + relw + biasf ready

    int cur = 0;
#pragma unroll 1
    for (int kt4 = 0; kt4 < len; ++kt4) {
        int kt = k_b + kt4;
        const float* bias = biasf + cur * 64;

        bool active = (64 * kt <= qmaxw);           // wave-uniform; NO break
        bool maskt = (64 * kt + 63 > q0 + 32 * w);  // tile crosses diagonal
        if (active) {
#pragma unroll
            for (int h2 = 0; h2 < 2; ++h2) {
                // ---- seed C with rel+bias-20 (local) or -20, S += K^T Q ----
                f32x16 S;
                if (islocal) {
                    int rbase = 64 * kt4 + 32 * h2 + 4 * hi + 127 - qrel;
#pragma unroll
                    for (int g = 0; g < 4; ++g) {
                        f32x4 bv = *(const f32x4*)&bias[32 * h2 + 8 * g + 4 * hi];
#pragma unroll
                        for (int j = 0; j < 4; ++j)
                            S[4 * g + j] = bv[j] + relw[rbase + 8 * g + j];
                    }
                } else {
                    S = (f32x16){-20.f,-20.f,-20.f,-20.f,-20.f,-20.f,-20.f,-20.f,
                                 -20.f,-20.f,-20.f,-20.f,-20.f,-20.f,-20.f,-20.f};
                }
                __builtin_amdgcn_s_setprio(1);
#pragma unroll
                for (int mq = 0; mq < 4; ++mq) {
                    const bf16x8 kf = *(const bf16x8*)&Ks[(h2 * 4 + mq) * 512 + hivl];
                    S = MFMA32(kf, qf[mq], S);
                }
                __builtin_amdgcn_s_setprio(0);
                // lane: q = qglob; k = 64kt + 32h2 + (r&3) + 8(r>>2) + 4hi

                if (maskt) {
                    int koff = 64 * kt + 32 * h2 + 4 * hi - qglob;
#pragma unroll
                    for (int r = 0; r < 16; ++r) {
                        int kk = (r & 3) + 8 * (r >> 2);
                        if (koff + kk > 0) S[r] = -1e30f;
                    }
                }
                // ---- fixed-exponent softmax: P = exp2(S), S pre-offset -20 ----
                float ps = 0.f;
#pragma unroll
                for (int r = 0; r < 16; ++r) {
                    float p = exp2f(S[r]);
                    S[r] = p; ps += p;
                }
                ps += __shfl_xor(ps, 32);
                lsum += ps;

                // ---- P -> bf16 frags via v_permlane32_swap_b32, PV ----
                __builtin_amdgcn_s_setprio(1);
#pragma unroll
                for (int kq = 0; kq < 2; ++kq) {
                    int ra = 8 * kq;
                    unsigned int x0 = cvtpk(S[ra + 0], S[ra + 1]);
                    unsigned int x1 = cvtpk(S[ra + 2], S[ra + 3]);
                    unsigned int y0 = cvtpk(S[ra + 4], S[ra + 5]);
                    unsigned int y1 = cvtpk(S[ra + 6], S[ra + 7]);
                    asm("v_permlane32_swap_b32 %0, %1" : "+v"(x0), "+v"(y0));
                    asm("v_permlane32_swap_b32 %0, %1" : "+v"(x1), "+v"(y1));
                    u32x4 fw;
                    fw[0] = x0; fw[1] = x1; fw[2] = y0; fw[3] = y1;
                    const bf16x8 pf = __builtin_bit_cast(bf16x8, fw);
                    int c2 = h2 * 2 + kq;
                    const bf16x8 vf0 = *(const bf16x8*)&Vt[c2 * 1024 + hivl];
                    const bf16x8 vf1 = *(const bf16x8*)&Vt[c2 * 1024 + 512 + hivl];
                    O0 = MFMA32(vf0, pf, O0);
                    O1 = MFMA32(vf1, pf, O1);
                }
                __builtin_amdgcn_s_setprio(0);
            }
        }
        __syncthreads();   // all waves done READING Ks/Vt for tile kt

        // ---- write staged tile kt+1 from regs; start loads for kt+2 ----
        if (kt4 + 1 < len) {
            *(u16x8*)&Ks[t * 8] = krA;
            *(u16x8*)&Ks[2048 + t * 8] = krB;
            *(u16x8*)&Vt[t * 8] = vrA;
            *(u16x8*)&Vt[2048 + t * 8] = vrB;
            int nb = cur ^ 1;
            if (islocal && t < 16)
                ((f32x4*)(biasf + nb * 64))[t] =
                    ((const f32x4*)(vtpf + (size_t)(kt + 1) * 64))[t];
            if (kt4 + 2 < len) {
                const unsigned short* gk = Ktiles + (size_t)(kt + 2) * 4096;
                const unsigned short* gv = Vtiles + (size_t)(kt + 2) * 4096;
                krA = *(const u16x8*)(gk + t * 8);
                krB = *(const u16x8*)(gk + 2048 + t * 8);
                vrA = *(const u16x8*)(gv + t * 8);
                vrB = *(const u16x8*)(gv + 2048 + t * 8);
            }
            __syncthreads();   // tile kt+1 visible to all waves
            cur = nb;
        }
    }

    // ---- partial dump: [dp 32][q 128] u32 (bf16 pair), then l ----
    float* pp = part + (size_t)bid * PSTRIDE;
    unsigned int* po = (unsigned int*)pp;
#pragma unroll
    for (int g = 0; g < 4; ++g) {
        unsigned int w0 = cvtpk(O0[4 * g + 0], O0[4 * g + 1]);
        unsigned int w1 = cvtpk(O0[4 * g + 2], O0[4 * g + 3]);
        unsigned int w2 = cvtpk(O1[4 * g + 0], O1[4 * g + 1]);
        unsigned int w3 = cvtpk(O1[4 * g + 2], O1[4 * g + 3]);
        int dp0 = 4 * g + 2 * hi;
        po[dp0 * 128 + qrel] = w0;
        po[(dp0 + 1) * 128 + qrel] = w1;
        po[(16 + dp0) * 128 + qrel] = w2;
        po[(16 + dp0 + 1) * 128 + qrel] = w3;
    }
    if (hi == 0) pp[4096 + qrel] = lsum;
}

// Combine strips of each (bhx, q128-block): fixed common exponent -> plain sum.
__global__ __launch_bounds__(128) void merge_kernel(
    const float* __restrict__ part, float* __restrict__ out) {
    int bid = blockIdx.x;          // 512 = 16 i x 32 bhx
    int bhx = bid & 31, i = bid >> 5;
    int bh = (bhx & 7) * 4 + (bhx >> 3);
    int n = (2 * i + 7) / 6;
    int sb = 0;
    for (int ii = 15; ii > i; --ii) sb += (2 * ii + 7) / 6;
    int t = threadIdx.x;           // q = t

    float den = 0.f;
#pragma unroll
    for (int s2 = 0; s2 < 6; ++s2)
        if (s2 < n)
            den += part[(size_t)((sb + s2) * 32 + bhx) * PSTRIDE + 4096 + t];
    float inv = 1.0f / den;

    size_t obase = (size_t)bh * TL * 64 + (size_t)(128 * i + t) * 64;
    for (int seg = 0; seg < 4; ++seg) {
        float o[16];
#pragma unroll
        for (int j = 0; j < 16; ++j) o[j] = 0.f;
#pragma unroll
        for (int s2 = 0; s2 < 6; ++s2) {
            if (s2 < n) {
                const unsigned int* po =
                    (const unsigned int*)(part + (size_t)((sb + s2) * 32 + bhx) * PSTRIDE);
#pragma unroll
                for (int j = 0; j < 8; ++j) {
                    unsigned int wv = po[(seg * 8 + j) * 128 + t];
                    o[2 * j]     += __uint_as_float((wv & 0xffffu) << 16);
                    o[2 * j + 1] += __uint_as_float(wv & 0xffff0000u);
                }
            }
        }
#pragma unroll
        for (int j = 0; j < 16; ++j) o[j] *= inv;
#pragma unroll
        for (int c = 0; c < 4; ++c)
            *(f32x4*)(out + obase + seg * 16 + 4 * c) = *(const f32x4*)&o[4 * c];
    }
}

extern "C" void kernel_launch(void* const* d_in, const int* in_sizes, int n_in,
                              void* d_out, int out_size, void* d_ws, size_t ws_size,
                              hipStream_t stream) {
    const float* query = (const float*)d_in[0];
    const float* key = (const float*)d_in[1];
    const float* value = (const float*)d_in[2];
    const float* rel_pos_w = (const float*)d_in[5];
    const float* mlp_w = (const float*)d_in[8];
    float* out = (float*)d_out;

    unsigned short* Kb = (unsigned short*)d_ws;          // 8 MiB
    unsigned short* Vtb = Kb + 32 * 32 * 4096;           // 8 MiB
    float* rel_sf = (float*)(Vtb + 32 * 32 * 4096);      // 4*4096 f32
    float* vtbf = rel_sf + 4 * 4096;                     // 32768 f32
    float* part = vtbf + 32768;                          // 1632 * 4352 f32 ~ 28.4 MiB

    preconv_kernel<<<2048, 256, 0, stream>>>(key, value, mlp_w, rel_pos_w,
                                             Kb, Vtb, vtbf, rel_sf);
    attn_kernel<<<1632, 256, 0, stream>>>(query, Kb, Vtb, rel_sf, vtbf, part);
    merge_kernel<<<512, 128, 0, stream>>>(part, out);
}